// Round 13
// baseline (225.096 us; speedup 1.0000x reference)
//
#include <hip/hip_runtime.h>
#include <math.h>

typedef _Float16 h2 __attribute__((ext_vector_type(2)));
typedef _Float16 f16x8 __attribute__((ext_vector_type(8)));
typedef float f32x4 __attribute__((ext_vector_type(4)));

// ws layout (floats):
//   [0, 24576)       T [3][64][128] f32 (b0 folded into axis 0)
//   [24576, 24704)   (unused)
//   [24704, 24832)   w2n[128]
//   [24832, 33024)   Wf: W1n^T f16 B-fragments, 8192 h2

// Single setup kernel, 196 blocks x 128 threads:
//   blocks 0..191  -> T rows (w0scale computed inline, float4 norms)
//   blocks 192..195 -> Wf fragments for kk = bid-192 (s1 norms 128-wide)
//   block 192 also  -> w2n
__global__ void setup(const float* __restrict__ expr,
                      const float* __restrict__ jqw,
                      const float* __restrict__ flx,
                      const float* __restrict__ fly,
                      const float* __restrict__ flz,
                      const float* __restrict__ w0v,
                      const float* __restrict__ w0g,
                      const float* __restrict__ b0,
                      const float* __restrict__ w1v,
                      const float* __restrict__ w1g,
                      const float* __restrict__ w2v,
                      const float* __restrict__ w2g,
                      float* __restrict__ T,
                      float* __restrict__ w2n,
                      h2* __restrict__ Wf) {
    __shared__ float smem[128];
    int bid = blockIdx.x;
    int t = threadIdx.x;

    if (bid < 192) {
        int a = bid >> 6;   // axis
        int l = bid & 63;   // grid row
        const float* fl = (a == 0) ? flx : (a == 1) ? fly : flz;
        if (t < 32) {
            float s = 0.f;
#pragma unroll 8
            for (int i = 0; i < 80; ++i) s += expr[i] * fl[(i * 64 + l) * 32 + t];
            smem[t] = s;
        } else if (t < 64) {
            int c = t - 32;
            float s = 0.f;
#pragma unroll
            for (int i = 0; i < 16; ++i) s += jqw[i] * fl[((80 + i) * 64 + l) * 32 + c];
            smem[32 + c] = s;
        }
        __syncthreads();
        int j = t;  // output channel
        const float4* w4 = reinterpret_cast<const float4*>(w0v + j * 192);
        float ns = 0.f;
#pragma unroll
        for (int q = 0; q < 48; ++q) {
            float4 v = w4[q];
            ns += v.x * v.x + v.y * v.y + v.z * v.z + v.w * v.w;
        }
        float scale = w0g[j] / sqrtf(ns);
        float acc = 0.f;
#pragma unroll 8
        for (int c = 0; c < 32; ++c) acc += w0v[j * 192 + a * 32 + c] * smem[c];
#pragma unroll 8
        for (int c = 0; c < 32; ++c) acc += w0v[j * 192 + 96 + a * 32 + c] * smem[32 + c];
        acc *= scale;
        if (a == 0) acc += b0[j];
        T[(a * 64 + l) * 128 + j] = acc;
    } else {
        int b = bid - 192;  // kk = 0..3
        // s1[n] = w1g[n] / ||w1v row n||, computed 128-wide with float4 loads
        {
            const float4* w4 = reinterpret_cast<const float4*>(w1v + t * 128);
            float n1 = 0.f;
#pragma unroll
            for (int q = 0; q < 32; ++q) {
                float4 v = w4[q];
                n1 += v.x * v.x + v.y * v.y + v.z * v.z + v.w * v.w;
            }
            smem[t] = w1g[t] / sqrtf(n1);
        }
        __syncthreads();
        if (b == 0) {
            const float4* w4 = reinterpret_cast<const float4*>(w2v);
            float n2 = 0.f;
#pragma unroll
            for (int q = 0; q < 32; ++q) {
                float4 v = w4[q];
                n2 += v.x * v.x + v.y * v.y + v.z * v.z + v.w * v.w;
            }
            w2n[t] = w2v[t] * (w2g[0] / sqrtf(n2));
        }
        // This block's 2048 Wf pairs: pi = b*2048 + t*16 + u
#pragma unroll
        for (int u = 0; u < 16; ++u) {
            int pi = b * 2048 + t * 16 + u;
            int jp = pi & 3;
            int lane = (pi >> 2) & 63;
            int f = pi >> 8;            // kk*8 + nt
            int kk = f >> 3, nt = f & 7;
            int n = nt * 16 + (lane & 15);
            int k = kk * 32 + (lane >> 4) * 8 + jp * 2;
            float s = smem[n];
            h2 v;
            v.x = (_Float16)(w1v[n * 128 + k] * s);
            v.y = (_Float16)(w1v[n * 128 + k + 1] * s);
            Wf[pi] = v;
        }
    }
}

// U table in LDS: per row r (192 rows), 32 interleaved 16B chunks:
//   chunk 2c   = T[r] halfs 8c..8c+7, chunk 2c+1 = T[r+1]-T[r] (0 at row 63)
// Row stride = 33 chunks (528 B) -> rows spread across bank groups.
#define U_ROW_CHUNKS 33
#define LDS_U_H2 (192 * U_ROW_CHUNKS * 4)   // 25344 h2 = 101376 B

template <int CTRL>
static __device__ __forceinline__ float dpp_ror_add(float x) {
    int yi = __builtin_amdgcn_update_dpp(0, __builtin_bit_cast(int, x),
                                         CTRL, 0xF, 0xF, false);
    return x + __builtin_bit_cast(float, yi);
}

__launch_bounds__(512)
__attribute__((amdgpu_waves_per_eu(2)))   // 256 unified regs/wave: 128 Bf + 32 acc + ~96 arch
__global__ void mlp_mfma(const float* __restrict__ xyz,
                         const float* __restrict__ Tg,
                         const f32x4* __restrict__ Wfrag,
                         const float* __restrict__ w2ng,
                         const float* __restrict__ b1,
                         const float* __restrict__ b2p,
                         float* __restrict__ out, int npts) {
    __shared__ __align__(16) h2 tT[LDS_U_H2];
    int tid = threadIdx.x;

    // Stage T (f32) -> interleaved {T, delta} f16 chunks.
    for (int u = tid; u < 12288; u += 512) {
        int r = u >> 6;        // 0..191
        int p = u & 63;        // h2-pair within row
        int rl = r & 63;
        float t0 = Tg[2 * u], t1 = Tg[2 * u + 1];
        float d0 = 0.f, d1 = 0.f;
        if (rl != 63) {
            d0 = Tg[2 * u + 128] - t0;
            d1 = Tg[2 * u + 129] - t1;
        }
        int base = (r * U_ROW_CHUNKS + 2 * (p >> 2)) * 4 + (p & 3);
        h2 tv; tv.x = (_Float16)t0; tv.y = (_Float16)t1;
        h2 dv; dv.x = (_Float16)d0; dv.y = (_Float16)d1;
        tT[base] = tv;       // T chunk
        tT[base + 4] = dv;   // delta chunk (next 16B)
    }
    __syncthreads();

    int lane = tid & 63;
    int lp = lane & 15;
    int lg = lane >> 4;

    // Layer-1 B-fragments pinned in registers (unified-file AGPRs).
    f32x4 Bf[4][8];
#pragma unroll
    for (int kk = 0; kk < 4; ++kk)
#pragma unroll
        for (int nt = 0; nt < 8; ++nt)
            Bf[kk][nt] = Wfrag[(((kk * 8 + nt) << 6) | lane)];
#pragma unroll
    for (int kk = 0; kk < 4; ++kk)
#pragma unroll
        for (int nt = 0; nt < 8; ++nt)
            asm volatile("" : "+v"(Bf[kk][nt]));

    float b1r[8], w2r[8];
#pragma unroll
    for (int nt = 0; nt < 8; ++nt) {
        b1r[nt] = b1[nt * 16 + lp];
        w2r[nt] = w2ng[nt * 16 + lp];
    }
    float b2 = b2p[0];

    int waveid = blockIdx.x * 8 + (tid >> 6);
    int nwaves = gridDim.x * 8;
    int ntiles = (npts + 15) >> 4;

    // prefetch first tile's xyz
    float cx, cy, cz;
    {
        int pc = min((min(waveid, ntiles - 1) << 4) + lp, npts - 1);
        cx = xyz[pc * 3 + 0];
        cy = xyz[pc * 3 + 1];
        cz = xyz[pc * 3 + 2];
    }

#pragma unroll 1
    for (int tile = waveid; tile < ntiles; tile += nwaves) {
        // prefetch next tile's xyz (hides under this tile's compute)
        float nx, ny, nz;
        {
            int pr = min(tile + nwaves, ntiles - 1);
            int pc = min((pr << 4) + lp, npts - 1);
            nx = xyz[pc * 3 + 0];
            ny = xyz[pc * 3 + 1];
            nz = xyz[pc * 3 + 2];
        }

        // ---- A fragments: hA[kk] = relu(h0[pt lp][kk*32 + lg*8 + 0..7]) ----
        f16x8 hA[4];
#pragma unroll
        for (int a = 0; a < 3; ++a) {
            float v = (a == 0) ? cx : (a == 1) ? cy : cz;
            v = fminf(fmaxf(v, 0.f), 1.f) * 63.f;
            float fv = floorf(v);
            int li = (int)fv;
            _Float16 w = (_Float16)(v - fv);
            f16x8 w8 = {w, w, w, w, w, w, w, w};
            int Rb = (a * 64 + li) * U_ROW_CHUNKS;
#pragma unroll
            for (int kk = 0; kk < 4; ++kk) {
                int ci = Rb + 2 * (kk * 4 + lg);
                f16x8 t8 = *reinterpret_cast<const f16x8*>(&tT[ci * 4]);
                f16x8 d8 = *reinterpret_cast<const f16x8*>(&tT[ci * 4 + 4]);
                if (a == 0)
                    hA[kk] = t8 + w8 * d8;           // v_pk_fma
                else
                    hA[kk] = hA[kk] + (t8 + w8 * d8);
            }
        }
        f16x8 z8 = (f16x8){0, 0, 0, 0, 0, 0, 0, 0};
#pragma unroll
        for (int kk = 0; kk < 4; ++kk)
            hA[kk] = __builtin_elementwise_max(hA[kk], z8);

        // ---- Layer 1 MFMA, b1 folded into acc init ----
        f32x4 acc[8];
#pragma unroll
        for (int nt = 0; nt < 8; ++nt)
            acc[nt] = (f32x4){b1r[nt], b1r[nt], b1r[nt], b1r[nt]};

#pragma unroll
        for (int kk = 0; kk < 4; ++kk)
#pragma unroll
            for (int nt = 0; nt < 8; ++nt)
                acc[nt] = __builtin_amdgcn_mfma_f32_16x16x32_f16(
                    hA[kk], __builtin_bit_cast(f16x8, Bf[kk][nt]), acc[nt], 0, 0, 0);

        // ---- Layer 2 + epilogue ----
        float part0 = 0.f, part1 = 0.f, part2 = 0.f, part3 = 0.f;
#pragma unroll
        for (int nt = 0; nt < 8; ++nt) {
            part0 += w2r[nt] * fmaxf(acc[nt][0], 0.f);
            part1 += w2r[nt] * fmaxf(acc[nt][1], 0.f);
            part2 += w2r[nt] * fmaxf(acc[nt][2], 0.f);
            part3 += w2r[nt] * fmaxf(acc[nt][3], 0.f);
        }
        part0 = dpp_ror_add<0x128>(part0);
        part1 = dpp_ror_add<0x128>(part1);
        part2 = dpp_ror_add<0x128>(part2);
        part3 = dpp_ror_add<0x128>(part3);
        part0 = dpp_ror_add<0x124>(part0);
        part1 = dpp_ror_add<0x124>(part1);
        part2 = dpp_ror_add<0x124>(part2);
        part3 = dpp_ror_add<0x124>(part3);
        part0 = dpp_ror_add<0x122>(part0);
        part1 = dpp_ror_add<0x122>(part1);
        part2 = dpp_ror_add<0x122>(part2);
        part3 = dpp_ror_add<0x122>(part3);
        part0 = dpp_ror_add<0x121>(part0);
        part1 = dpp_ror_add<0x121>(part1);
        part2 = dpp_ror_add<0x121>(part2);
        part3 = dpp_ror_add<0x121>(part3);

        // lane lp<4 stores out[m0 + 4*lg + lp]
        float sel = part3;
        sel = (lp == 2) ? part2 : sel;
        sel = (lp == 1) ? part1 : sel;
        sel = (lp == 0) ? part0 : sel;
        int mi = (tile << 4) + (lg << 2) + lp;
        if (lp < 4 && mi < npts) out[mi] = sel + b2;

        cx = nx; cy = ny; cz = nz;
    }
}

extern "C" void kernel_launch(void* const* d_in, const int* in_sizes, int n_in,
                              void* d_out, int out_size, void* d_ws, size_t ws_size,
                              hipStream_t stream) {
    const float* expr = (const float*)d_in[0];
    const float* jqw  = (const float*)d_in[1];
    const float* xyz  = (const float*)d_in[2];
    const float* flx  = (const float*)d_in[3];
    const float* fly  = (const float*)d_in[4];
    const float* flz  = (const float*)d_in[5];
    const float* w0v  = (const float*)d_in[6];
    const float* w0g  = (const float*)d_in[7];
    const float* b0   = (const float*)d_in[8];
    const float* w1v  = (const float*)d_in[9];
    const float* w1g  = (const float*)d_in[10];
    const float* b1   = (const float*)d_in[11];
    const float* w2v  = (const float*)d_in[12];
    const float* w2g  = (const float*)d_in[13];
    const float* b2   = (const float*)d_in[14];

    float* ws = (float*)d_ws;
    float* T   = ws;                     // 24576 floats
    float* w2n = ws + 24704;             // 128
    h2*    Wf  = (h2*)(ws + 24832);      // 8192 h2

    int npts = in_sizes[2] / 3;

    setup<<<196, 128, 0, stream>>>(expr, jqw, flx, fly, flz,
                                   w0v, w0g, b0, w1v, w1g, w2v, w2g,
                                   T, w2n, Wf);
    mlp_mfma<<<256, 512, 0, stream>>>(xyz, T, (const f32x4*)Wf, w2n, b1, b2,
                                      (float*)d_out, npts);
}

// Round 14
// 211.678 us; speedup vs baseline: 1.0634x; 1.0634x over previous
//
#include <hip/hip_runtime.h>
#include <math.h>

typedef _Float16 h2 __attribute__((ext_vector_type(2)));
typedef _Float16 f16x8 __attribute__((ext_vector_type(8)));
typedef float f32x4 __attribute__((ext_vector_type(4)));

// ws layout (floats):
//   [0, 24576)       T [3][64][128] f32 (b0 folded into axis 0)
//   [24576, 24704)   w0scale[128]
//   [24704, 24832)   w2n[128]
//   [24832, 33024)   Wf: W1n^T f16 B-fragments, 8192 h2
//   [33024, 45312)   bsjaw [3][64][64]  (c<32: bs, c>=32: jaw)

// k1, 26 blocks x 512:
//   blocks 0..11 : bs  values, one per thread (coalesced in c)
//   blocks 12..23: jaw values, one per thread
//   block 24     : w0v -> LDS (coalesced), w0scale[128]
//   block 25     : w1v -> LDS (coalesced), s1, w2n, Wf fragments
__global__ void setup1(const float* __restrict__ expr,
                       const float* __restrict__ jqw,
                       const float* __restrict__ flx,
                       const float* __restrict__ fly,
                       const float* __restrict__ flz,
                       const float* __restrict__ w0v,
                       const float* __restrict__ w0g,
                       const float* __restrict__ w1v,
                       const float* __restrict__ w1g,
                       const float* __restrict__ w2v,
                       const float* __restrict__ w2g,
                       float* __restrict__ w0scale,
                       float* __restrict__ w2n,
                       h2* __restrict__ Wf,
                       float* __restrict__ bsjaw) {
    __shared__ float lds[24576 + 128];
    int bid = blockIdx.x;
    int t = threadIdx.x;

    if (bid < 12) {              // bs: idx in [0, 6144)
        int idx = bid * 512 + t;
        int c = idx & 31;
        int l = (idx >> 5) & 63;
        int a = idx >> 11;
        const float* fl = (a == 0) ? flx : (a == 1) ? fly : flz;
        float s = 0.f;
#pragma unroll 8
        for (int i = 0; i < 80; ++i) s += expr[i] * fl[(i * 64 + l) * 32 + c];
        bsjaw[(a * 64 + l) * 64 + c] = s;
    } else if (bid < 24) {       // jaw
        int idx = (bid - 12) * 512 + t;
        int c = idx & 31;
        int l = (idx >> 5) & 63;
        int a = idx >> 11;
        const float* fl = (a == 0) ? flx : (a == 1) ? fly : flz;
        float s = 0.f;
#pragma unroll
        for (int i = 0; i < 16; ++i) s += jqw[i] * fl[((80 + i) * 64 + l) * 32 + c];
        bsjaw[(a * 64 + l) * 64 + 32 + c] = s;
    } else if (bid == 24) {      // w0scale
        for (int u = t; u < 24576; u += 512) lds[u] = w0v[u];
        __syncthreads();
        if (t < 128) {
            float ns = 0.f;
#pragma unroll 16
            for (int c = 0; c < 192; ++c) { float v = lds[t * 192 + c]; ns += v * v; }
            w0scale[t] = w0g[t] / sqrtf(ns);
        }
    } else {                     // w1 -> s1 -> Wf; w2n
        for (int u = t; u < 16384; u += 512) lds[u] = w1v[u];
        __syncthreads();
        if (t < 128) {
            float n1 = 0.f;
#pragma unroll 16
            for (int k = 0; k < 128; ++k) { float v = lds[t * 128 + k]; n1 += v * v; }
            lds[24576 + t] = w1g[t] / sqrtf(n1);
            float n2 = 0.f;
#pragma unroll 16
            for (int k = 0; k < 128; ++k) { float v = w2v[k]; n2 += v * v; }
            w2n[t] = w2v[t] * (w2g[0] / sqrtf(n2));
        }
        __syncthreads();
#pragma unroll
        for (int u = 0; u < 16; ++u) {
            int pi = t * 16 + u;           // [0, 8192)
            int jp = pi & 3;
            int lane = (pi >> 2) & 63;
            int f = pi >> 8;               // kk*8 + nt
            int kk = f >> 3, nt = f & 7;
            int n = nt * 16 + (lane & 15);
            int k = kk * 32 + (lane >> 4) * 8 + jp * 2;
            float s = lds[24576 + n];
            h2 v;
            v.x = (_Float16)(lds[n * 128 + k] * s);
            v.y = (_Float16)(lds[n * 128 + k + 1] * s);
            Wf[pi] = v;
        }
    }
}

// k2, 24 blocks x 128: T[(a*64+l)*128+j] from bsjaw (LDS broadcast) and w0v.
__global__ void setup2(const float* __restrict__ w0v,
                       const float* __restrict__ b0,
                       const float* __restrict__ w0scale,
                       const float* __restrict__ bsjaw,
                       float* __restrict__ T) {
    __shared__ float rows[512];
    int bid = blockIdx.x;
    int t = threadIdx.x;
    int a = bid >> 3;
    int l0 = (bid & 7) << 3;
    for (int u = t; u < 512; u += 128)
        rows[u] = bsjaw[(a * 64 + l0) * 64 + u];
    __syncthreads();
    int j = t;
    float wa[32], wb[32];
#pragma unroll
    for (int c = 0; c < 32; ++c) {
        wa[c] = w0v[j * 192 + a * 32 + c];
        wb[c] = w0v[j * 192 + 96 + a * 32 + c];
    }
    float sc = w0scale[j];
    float bb = (a == 0) ? b0[j] : 0.f;
#pragma unroll
    for (int dl = 0; dl < 8; ++dl) {
        float acc = 0.f;
#pragma unroll
        for (int c = 0; c < 32; ++c) {
            acc += wa[c] * rows[dl * 64 + c];
            acc += wb[c] * rows[dl * 64 + 32 + c];
        }
        T[(a * 64 + l0 + dl) * 128 + j] = acc * sc + bb;
    }
}

// U table in LDS: per row r (192 rows), 32 interleaved 16B chunks:
//   chunk 2c   = T[r] halfs 8c..8c+7, chunk 2c+1 = T[r+1]-T[r] (0 at row 63)
// Row stride = 33 chunks (528 B) -> rows spread across bank groups.
#define U_ROW_CHUNKS 33
#define LDS_U_H2 (192 * U_ROW_CHUNKS * 4)   // 25344 h2 = 101376 B

template <int CTRL>
static __device__ __forceinline__ float dpp_ror_add(float x) {
    int yi = __builtin_amdgcn_update_dpp(0, __builtin_bit_cast(int, x),
                                         CTRL, 0xF, 0xF, false);
    return x + __builtin_bit_cast(float, yi);
}

__launch_bounds__(512)
__attribute__((amdgpu_waves_per_eu(2)))   // 256 unified regs/wave: 128 Bf + 32 acc + ~96 arch
__global__ void mlp_mfma(const float* __restrict__ xyz,
                         const float* __restrict__ Tg,
                         const f32x4* __restrict__ Wfrag,
                         const float* __restrict__ w2ng,
                         const float* __restrict__ b1,
                         const float* __restrict__ b2p,
                         float* __restrict__ out, int npts) {
    __shared__ __align__(16) h2 tT[LDS_U_H2];
    int tid = threadIdx.x;

    // Stage T (f32) -> interleaved {T, delta} f16 chunks.
    for (int u = tid; u < 12288; u += 512) {
        int r = u >> 6;        // 0..191
        int p = u & 63;        // h2-pair within row
        int rl = r & 63;
        float t0 = Tg[2 * u], t1 = Tg[2 * u + 1];
        float d0 = 0.f, d1 = 0.f;
        if (rl != 63) {
            d0 = Tg[2 * u + 128] - t0;
            d1 = Tg[2 * u + 129] - t1;
        }
        int base = (r * U_ROW_CHUNKS + 2 * (p >> 2)) * 4 + (p & 3);
        h2 tv; tv.x = (_Float16)t0; tv.y = (_Float16)t1;
        h2 dv; dv.x = (_Float16)d0; dv.y = (_Float16)d1;
        tT[base] = tv;       // T chunk
        tT[base + 4] = dv;   // delta chunk (next 16B)
    }
    __syncthreads();

    int lane = tid & 63;
    int lp = lane & 15;
    int lg = lane >> 4;

    // Layer-1 B-fragments pinned in registers (unified-file AGPRs).
    f32x4 Bf[4][8];
#pragma unroll
    for (int kk = 0; kk < 4; ++kk)
#pragma unroll
        for (int nt = 0; nt < 8; ++nt)
            Bf[kk][nt] = Wfrag[(((kk * 8 + nt) << 6) | lane)];
#pragma unroll
    for (int kk = 0; kk < 4; ++kk)
#pragma unroll
        for (int nt = 0; nt < 8; ++nt)
            asm volatile("" : "+v"(Bf[kk][nt]));

    float b1r[8], w2r[8];
#pragma unroll
    for (int nt = 0; nt < 8; ++nt) {
        b1r[nt] = b1[nt * 16 + lp];
        w2r[nt] = w2ng[nt * 16 + lp];
    }
    float b2 = b2p[0];

    int waveid = blockIdx.x * 8 + (tid >> 6);
    int nwaves = gridDim.x * 8;
    int ntiles = (npts + 15) >> 4;

    // prefetch first tile's xyz
    float cx, cy, cz;
    {
        int pc = min((min(waveid, ntiles - 1) << 4) + lp, npts - 1);
        cx = xyz[pc * 3 + 0];
        cy = xyz[pc * 3 + 1];
        cz = xyz[pc * 3 + 2];
    }

#pragma unroll 1
    for (int tile = waveid; tile < ntiles; tile += nwaves) {
        // prefetch next tile's xyz (hides under this tile's compute)
        float nx, ny, nz;
        {
            int pr = min(tile + nwaves, ntiles - 1);
            int pc = min((pr << 4) + lp, npts - 1);
            nx = xyz[pc * 3 + 0];
            ny = xyz[pc * 3 + 1];
            nz = xyz[pc * 3 + 2];
        }

        // ---- A fragments: hA[kk] = relu(h0[pt lp][kk*32 + lg*8 + 0..7]) ----
        f16x8 hA[4];
#pragma unroll
        for (int a = 0; a < 3; ++a) {
            float v = (a == 0) ? cx : (a == 1) ? cy : cz;
            v = fminf(fmaxf(v, 0.f), 1.f) * 63.f;
            float fv = floorf(v);
            int li = (int)fv;
            _Float16 w = (_Float16)(v - fv);
            f16x8 w8 = {w, w, w, w, w, w, w, w};
            int Rb = (a * 64 + li) * U_ROW_CHUNKS;
#pragma unroll
            for (int kk = 0; kk < 4; ++kk) {
                int ci = Rb + 2 * (kk * 4 + lg);
                f16x8 t8 = *reinterpret_cast<const f16x8*>(&tT[ci * 4]);
                f16x8 d8 = *reinterpret_cast<const f16x8*>(&tT[ci * 4 + 4]);
                if (a == 0)
                    hA[kk] = t8 + w8 * d8;           // v_pk_fma
                else
                    hA[kk] = hA[kk] + (t8 + w8 * d8);
            }
        }
        f16x8 z8 = (f16x8){0, 0, 0, 0, 0, 0, 0, 0};
#pragma unroll
        for (int kk = 0; kk < 4; ++kk)
            hA[kk] = __builtin_elementwise_max(hA[kk], z8);

        // ---- Layer 1 MFMA, b1 folded into acc init ----
        f32x4 acc[8];
#pragma unroll
        for (int nt = 0; nt < 8; ++nt)
            acc[nt] = (f32x4){b1r[nt], b1r[nt], b1r[nt], b1r[nt]};

#pragma unroll
        for (int kk = 0; kk < 4; ++kk)
#pragma unroll
            for (int nt = 0; nt < 8; ++nt)
                acc[nt] = __builtin_amdgcn_mfma_f32_16x16x32_f16(
                    hA[kk], __builtin_bit_cast(f16x8, Bf[kk][nt]), acc[nt], 0, 0, 0);

        // ---- Layer 2 + epilogue ----
        float part0 = 0.f, part1 = 0.f, part2 = 0.f, part3 = 0.f;
#pragma unroll
        for (int nt = 0; nt < 8; ++nt) {
            part0 += w2r[nt] * fmaxf(acc[nt][0], 0.f);
            part1 += w2r[nt] * fmaxf(acc[nt][1], 0.f);
            part2 += w2r[nt] * fmaxf(acc[nt][2], 0.f);
            part3 += w2r[nt] * fmaxf(acc[nt][3], 0.f);
        }
        part0 = dpp_ror_add<0x128>(part0);
        part1 = dpp_ror_add<0x128>(part1);
        part2 = dpp_ror_add<0x128>(part2);
        part3 = dpp_ror_add<0x128>(part3);
        part0 = dpp_ror_add<0x124>(part0);
        part1 = dpp_ror_add<0x124>(part1);
        part2 = dpp_ror_add<0x124>(part2);
        part3 = dpp_ror_add<0x124>(part3);
        part0 = dpp_ror_add<0x122>(part0);
        part1 = dpp_ror_add<0x122>(part1);
        part2 = dpp_ror_add<0x122>(part2);
        part3 = dpp_ror_add<0x122>(part3);
        part0 = dpp_ror_add<0x121>(part0);
        part1 = dpp_ror_add<0x121>(part1);
        part2 = dpp_ror_add<0x121>(part2);
        part3 = dpp_ror_add<0x121>(part3);

        // lane lp<4 stores out[m0 + 4*lg + lp]
        float sel = part3;
        sel = (lp == 2) ? part2 : sel;
        sel = (lp == 1) ? part1 : sel;
        sel = (lp == 0) ? part0 : sel;
        int mi = (tile << 4) + (lg << 2) + lp;
        if (lp < 4 && mi < npts) out[mi] = sel + b2;

        cx = nx; cy = ny; cz = nz;
    }
}

extern "C" void kernel_launch(void* const* d_in, const int* in_sizes, int n_in,
                              void* d_out, int out_size, void* d_ws, size_t ws_size,
                              hipStream_t stream) {
    const float* expr = (const float*)d_in[0];
    const float* jqw  = (const float*)d_in[1];
    const float* xyz  = (const float*)d_in[2];
    const float* flx  = (const float*)d_in[3];
    const float* fly  = (const float*)d_in[4];
    const float* flz  = (const float*)d_in[5];
    const float* w0v  = (const float*)d_in[6];
    const float* w0g  = (const float*)d_in[7];
    const float* b0   = (const float*)d_in[8];
    const float* w1v  = (const float*)d_in[9];
    const float* w1g  = (const float*)d_in[10];
    const float* b1   = (const float*)d_in[11];
    const float* w2v  = (const float*)d_in[12];
    const float* w2g  = (const float*)d_in[13];
    const float* b2   = (const float*)d_in[14];

    float* ws = (float*)d_ws;
    float* T       = ws;                     // 24576 floats
    float* w0scale = ws + 24576;             // 128
    float* w2n     = ws + 24704;             // 128
    h2*    Wf      = (h2*)(ws + 24832);      // 8192 h2 -> [24832, 33024)
    float* bsjaw   = ws + 33024;             // 12288 floats

    int npts = in_sizes[2] / 3;

    setup1<<<26, 512, 0, stream>>>(expr, jqw, flx, fly, flz,
                                   w0v, w0g, w1v, w1g, w2v, w2g,
                                   w0scale, w2n, Wf, bsjaw);
    setup2<<<24, 128, 0, stream>>>(w0v, b0, w0scale, bsjaw, T);
    mlp_mfma<<<256, 512, 0, stream>>>(xyz, T, (const f32x4*)Wf, w2n, b1, b2,
                                      (float*)d_out, npts);
}